// Round 7
// baseline (230.259 us; speedup 1.0000x reference)
//
#include <hip/hip_runtime.h>
#include <math.h>

#define Bb 64
#define Qn 512
#define Kn 512
#define Cn 256
#define Hn 8
#define HDn 32
#define OUTn 256

typedef __bf16 bf16_t;
typedef __attribute__((ext_vector_type(4))) __bf16 bf16x4;
typedef __attribute__((ext_vector_type(8))) __bf16 bf16x8;
typedef __attribute__((ext_vector_type(4))) float f32x4;
typedef __attribute__((ext_vector_type(4))) unsigned int u32x4;

__device__ inline bf16_t tob(float f) {
    unsigned int u = __float_as_uint(f);
    u += 0x7fff + ((u >> 16) & 1);   // RNE
    unsigned short s = (unsigned short)(u >> 16);
    return __builtin_bit_cast(bf16_t, s);
}

// async global->LDS, 16B per lane; LDS dest = wave-uniform base + lane*16
__device__ inline void gl_lds16(const void* g, void* l) {
    __builtin_amdgcn_global_load_lds(
        (const __attribute__((address_space(1))) unsigned int*)g,
        (__attribute__((address_space(3))) unsigned int*)l, 16, 0, 0);
}

// ---------------- weight prep: transpose + cast to bf16 ----------------
__global__ __launch_bounds__(256) void prep_weights(
    const float* __restrict__ qw, const float* __restrict__ kw,
    const float* __restrict__ vw, const float* __restrict__ gw,
    const float* __restrict__ ow,
    bf16_t* __restrict__ wtq, bf16_t* __restrict__ wtk,
    bf16_t* __restrict__ wtv, bf16_t* __restrict__ wtg,
    bf16_t* __restrict__ wto)
{
    int tid = blockIdx.x * 256 + threadIdx.x;   // 0 .. 5*65536-1
    int mat = tid >> 16;
    int rem = tid & 65535;
    int a = rem >> 8;    // source row (k dim)
    int n = rem & 255;   // source col (n dim)
    const float* src = mat == 0 ? qw : mat == 1 ? kw : mat == 2 ? vw : mat == 3 ? gw : ow;
    bf16_t* dst = mat == 0 ? wtq : mat == 1 ? wtk : mat == 2 ? wtv : mat == 3 ? wtg : wto;
    dst[n * 256 + a] = tob(src[a * 256 + n]);
}

// ---------------- projections ----------------
// v is stored with a permuted k-axis so attention's PV step can consume P
// directly from the QK^T accumulator layout (no LDS transpose):
//   vbuf[d][kk] = V[pos][d],  kk = perm^-1(pos),
//   perm^-1 on low 5 bits: kk = p3<<4 | p2<<3 | p4<<2 | p1<<1 | p0.
#define ALDS_STRIDE 264   // 256 + 8 pad
__global__ __launch_bounds__(512) void proj_kernel(
    const float* __restrict__ qdata, const float* __restrict__ mdata,
    const bf16_t* __restrict__ wtq, const bf16_t* __restrict__ wtk,
    const bf16_t* __restrict__ wtv, const bf16_t* __restrict__ wtg,
    const float* __restrict__ gating_b,
    bf16_t* __restrict__ qb, bf16_t* __restrict__ kb,
    bf16_t* __restrict__ vTb, bf16_t* __restrict__ gateb)
{
    __shared__ bf16_t alds[64 * ALDS_STRIDE];
    const int side = blockIdx.y;          // 0: q_data, 1: m_data
    const int m0 = blockIdx.x * 64;
    const int tid = threadIdx.x;
    const int lane = tid & 63;
    const int w = tid >> 6;               // wave 0..7
    const int ch = w >> 2;                // 0: q|k, 1: gate|v
    const int ncb = (w & 3) * 64;
    const int c15 = lane & 15;
    const int rgrp = lane >> 4;
    const int kof = rgrp * 8;
    const float* X = side ? mdata : qdata;
    const bf16_t* Wt = side == 0 ? (ch == 0 ? wtq : wtg) : (ch == 0 ? wtk : wtv);
    const bool vout = (side == 1) && (ch == 1);

    #pragma unroll
    for (int i = 0; i < 8; i++) {
        int u = tid + i * 512;            // 4096 f32x4 units
        int row = u >> 6;
        int c4 = u & 63;
        f32x4 a4 = *reinterpret_cast<const f32x4*>(X + (size_t)(m0 + row) * 256 + c4 * 4);
        bf16_t* dst = &alds[row * ALDS_STRIDE + c4 * 4];
        #pragma unroll
        for (int j = 0; j < 4; j++) dst[j] = tob(a4[j]);
    }
    __syncthreads();

    f32x4 acc[4][4] = {};
    #pragma unroll
    for (int kc = 0; kc < 8; kc++) {
        bf16x8 am[4], bn[4];
        #pragma unroll
        for (int i = 0; i < 4; i++)
            am[i] = *reinterpret_cast<const bf16x8*>(&alds[(i * 16 + c15) * ALDS_STRIDE + kc * 32 + kof]);
        #pragma unroll
        for (int j = 0; j < 4; j++)
            bn[j] = *reinterpret_cast<const bf16x8*>(Wt + (ncb + j * 16 + c15) * 256 + kc * 32 + kof);
        #pragma unroll
        for (int i = 0; i < 4; i++)
            #pragma unroll
            for (int j = 0; j < 4; j++) {
                if (vout)
                    acc[i][j] = __builtin_amdgcn_mfma_f32_16x16x32_bf16(bn[j], am[i], acc[i][j], 0, 0, 0);
                else
                    acc[i][j] = __builtin_amdgcn_mfma_f32_16x16x32_bf16(am[i], bn[j], acc[i][j], 0, 0, 0);
            }
    }

    // q is pre-scaled by log2(e)/sqrt(32): softmax computes exp2 directly.
    const float scale = 0.17677669529663687f * 1.4426950408889634f;
    if (!vout) {
        #pragma unroll
        for (int j = 0; j < 4; j++) {
            int n = ncb + j * 16 + c15;
            int h = n >> 5, d = n & 31;
            #pragma unroll
            for (int i = 0; i < 4; i++) {
                #pragma unroll
                for (int r = 0; r < 4; r++) {
                    int m = m0 + i * 16 + rgrp * 4 + r;
                    int b = m >> 9, pos = m & 511;
                    float v = acc[i][j][r];
                    size_t idx = (((size_t)(b * Hn + h) * Qn + pos) << 5) + d;
                    if (side == 0) {
                        if (ch == 0) {
                            qb[idx] = tob(v * scale);
                        } else {
                            float g = 1.f / (1.f + __expf(-(v + gating_b[n])));
                            gateb[idx] = tob(g);
                        }
                    } else {
                        kb[idx] = tob(v);
                    }
                }
            }
        }
    } else {
        // transposed acc: lanes index m-rows (key positions), regs index n=(h,d)
        #pragma unroll
        for (int i = 0; i < 4; i++) {
            int m = m0 + i * 16 + c15;
            int b = m >> 9, pos = m & 511;
            int kk = (pos & ~31) | (((pos >> 3) & 1) << 4) | (((pos >> 2) & 1) << 3)
                   | (((pos >> 4) & 1) << 2) | (pos & 3);
            #pragma unroll
            for (int j = 0; j < 4; j++) {
                #pragma unroll
                for (int r = 0; r < 4; r++) {
                    int n = ncb + j * 16 + rgrp * 4 + r;
                    int h = n >> 5, d = n & 31;
                    vTb[((size_t)(b * Hn + h) * HDn + d) * Kn + kk] = tob(acc[i][j][r]);
                }
            }
        }
    }
}

// ---------------- fused attention (swapped QK^T, lane-local P) ------------
// R7: block = (b,h). K (32KB) + V (32KB) staged into LDS ONCE per block
// via global_load_lds (16 instrs/thread), ONE vmcnt(0)+barrier total; then
// qt=0..7 x 8 chunks run with ZERO barriers / manual waits -- waves fully
// decoupled. Rationale: R6 proved cache-traffic cuts pay (K/V /4 -> -14%)
// but 8.3K cycles/chunk-slot vs ~400 issue = still ~95% stall with all
// pipes <30%: the per-chunk vmcnt+barrier convoy was the residual
// serializer. This removes it AND cuts K/V global traffic another /8
// (staged once per (b,h), not once per qt-block).
// LDS = 64KB K/V + 16KB bias = exactly 80KB -> 2 blocks/CU; grid 512 =
// exactly 2 resident blocks/CU, zero tail.
// XCD-chunked remap p=(bid&7)*64+(bid>>3) (bijective, 512%8==0):
// same-b blocks (sharing bias[b]) co-locate on one XCD for L2 reuse.
// Bias: coop coalesced load -> regs (distance-1 prefetch, seamless across
// qt boundaries) -> per-wave LDS transpose (R2: direct reads cost 1.5x).
// Swizzles: K/V pre-swizzled at global SOURCE (linear gl_lds dest),
// swizzled LDS read (rule 21). VGPR <= 64 (R1: crossing 64 halves waves).
__global__ __launch_bounds__(256) void attn_kernel(
    const bf16_t* __restrict__ qb, const bf16_t* __restrict__ kb,
    const bf16_t* __restrict__ vTb, const bf16_t* __restrict__ gateb,
    const float* __restrict__ bias, const float* __restrict__ nbias,
    bf16_t* __restrict__ wab)
{
    __shared__ __align__(16) char klds[32768];       // K[512 rows][64B], swizzled
    __shared__ __align__(16) char vlds[32768];       // V[32 d-rows][1KB], swizzled
    __shared__ __align__(16) float blds[4][16 * 64]; // per-wave bias, XOR-swizzled
    const int bid = blockIdx.x;
    const int p = (bid & 7) * 64 + (bid >> 3);   // same-b blocks -> same XCD
    const int h = p & 7;
    const int b = p >> 3;
    const int tid = threadIdx.x;
    const int lane = tid & 63;
    const int wv = tid >> 6;
    const int c15 = lane & 15;
    const int rgrp = lane >> 4;
    const int kof = rgrp * 8;

    const bf16_t* qbase = qb + (size_t)(b * Hn + h) * Qn * HDn;
    const bf16_t* kbase = kb + (size_t)(b * Hn + h) * Kn * HDn;
    const bf16_t* vbase = vTb + (size_t)(b * Hn + h) * HDn * Kn;
    char* blw = (char*)blds[wv];

    // ---- stage ALL of K and V once (linear LDS, pre-swizzled source) ----
    #pragma unroll
    for (int i = 0; i < 8; i++) {
        int gr = i * 64 + (tid >> 2);                // K row 0..511
        size_t ksrc = ((size_t)gr << 6) + (size_t)(((tid & 3) << 4) ^ ((gr & 3) << 4));
        gl_lds16((const char*)kbase + ksrc, &klds[i * 4096 + wv * 1024]);
        int d = i * 4 + wv;                          // V d-row 0..31 (1KB each)
        size_t vsrc = ((size_t)d << 10) + (size_t)((lane << 4) ^ ((d & 7) << 4));
        gl_lds16((const char*)vbase + vsrc, &vlds[i * 4096 + wv * 1024]);
    }
    asm volatile("s_waitcnt vmcnt(0)" ::: "memory");
    __builtin_amdgcn_s_barrier();                    // the ONLY barrier

    const float LOG2E = 1.4426950408889634f;
    const float NML = -12.f * 1.4426950408889634f;   // -M*log2e, folded into QK^T C
    const f32x4 zML = {NML, NML, NML, NML};

    // ---- prologue: bias (qt=0, chunk 0) -> regs ----
    f32x4 bs[4];
    {
        const float* bR = bias + ((size_t)b * Qn + wv * 16) * Kn;
        const float* nR = nbias + ((size_t)h * Qn + wv * 16) * Kn;
        #pragma unroll
        for (int u = 0; u < 4; u++) {
            int row = u * 4 + rgrp;
            f32x4 x = *reinterpret_cast<const f32x4*>(bR + (size_t)row * Kn + c15 * 4);
            f32x4 y = *reinterpret_cast<const f32x4*>(nR + (size_t)row * Kn + c15 * 4);
            bs[u] = x + y;
        }
    }

    #pragma unroll 1
    for (int qt = 0; qt < 8; qt++) {
        const int q0 = qt * 64 + wv * 16;
        const float* bR = bias + ((size_t)b * Qn + q0) * Kn;
        const float* nR = nbias + ((size_t)h * Qn + q0) * Kn;

        bf16x8 aq = *reinterpret_cast<const bf16x8*>(qbase + (q0 + c15) * HDn + kof);
        f32x4 o[2] = {};
        f32x4 lsv = {0.f, 0.f, 0.f, 0.f};

        #pragma unroll 1
        for (int c = 0; c < 8; c++) {
            // ---- stage current bias regs -> per-wave LDS (XOR swizzle) ----
            #pragma unroll
            for (int u = 0; u < 4; u++) {
                int row = u * 4 + rgrp;
                *reinterpret_cast<f32x4*>(blw + (row << 8) + ((c15 << 4) ^ ((row & 7) << 4))) = bs[u];
            }
            // ---- prefetch next bias (next chunk, or next qt's chunk 0) ----
            if (c < 7 || qt < 7) {
                const float* pbR = (c < 7) ? bR : bR + (size_t)64 * Kn;
                const float* pnR = (c < 7) ? nR : nR + (size_t)64 * Kn;
                const int pcol = (c < 7) ? (c + 1) * 64 : 0;
                #pragma unroll
                for (int u = 0; u < 4; u++) {
                    int row = u * 4 + rgrp;
                    f32x4 x = *reinterpret_cast<const f32x4*>(pbR + (size_t)row * Kn + pcol + c15 * 4);
                    f32x4 y = *reinterpret_cast<const f32x4*>(pnR + (size_t)row * Kn + pcol + c15 * 4);
                    bs[u] = x + y;
                }
            }
            asm volatile("" ::: "memory");    // order: bias LDS writes before reads
            // ---- QK^T from LDS K (swizzled read) ----
            f32x4 sc[4];
            #pragma unroll
            for (int t = 0; t < 4; t++) {
                int kr = c * 64 + t * 16 + c15;
                bf16x8 kf = *reinterpret_cast<const bf16x8*>(&klds[(kr << 6) + ((rgrp << 4) ^ ((kr & 3) << 4))]);
                sc[t] = __builtin_amdgcn_mfma_f32_16x16x32_bf16(kf, aq, zML, 0, 0, 0);
            }
            // ---- softmax: e = exp2(fma(bb, L, sc)); pack P via cvt_pk ----
            f32x4 es[4];
            #pragma unroll
            for (int t = 0; t < 4; t++) {
                f32x4 bb = *reinterpret_cast<const f32x4*>(blw + (c15 << 8) + (((t << 6) | (rgrp << 4)) ^ ((c15 & 7) << 4)));
                #pragma unroll
                for (int r = 0; r < 4; r++)
                    es[t][r] = __builtin_amdgcn_exp2f(fmaf(bb[r], LOG2E, sc[t][r]));
                lsv += es[t];
            }
            unsigned int pw[8];
            #pragma unroll
            for (int t = 0; t < 4; t++) {
                asm("v_cvt_pk_bf16_f32 %0, %1, %2" : "=v"(pw[t * 2 + 0]) : "v"(es[t][0]), "v"(es[t][1]));
                asm("v_cvt_pk_bf16_f32 %0, %1, %2" : "=v"(pw[t * 2 + 1]) : "v"(es[t][2]), "v"(es[t][3]));
            }
            u32x4 a0 = {pw[0], pw[1], pw[2], pw[3]};
            u32x4 a1 = {pw[4], pw[5], pw[6], pw[7]};
            bf16x8 pa0 = __builtin_bit_cast(bf16x8, a0);
            bf16x8 pa1 = __builtin_bit_cast(bf16x8, a1);
            // ---- PV from LDS V (swizzled read), P in-register ----
            #pragma unroll
            for (int sub = 0; sub < 2; sub++) {
                bf16x8 ap = sub == 0 ? pa0 : pa1;
                #pragma unroll
                for (int nt = 0; nt < 2; nt++) {
                    int vr = nt * 16 + c15;
                    bf16x8 bv = *reinterpret_cast<const bf16x8*>(&vlds[(vr << 10) + c * 128
                                    + ((((sub << 6) | (rgrp << 4)) ^ ((vr & 7) << 4)))]);
                    o[nt] = __builtin_amdgcn_mfma_f32_16x16x32_bf16(ap, bv, o[nt], 0, 0, 0);
                }
            }
        }

        float lsum = (lsv[0] + lsv[1]) + (lsv[2] + lsv[3]);
        lsum += __shfl_xor(lsum, 16, 64);
        lsum += __shfl_xor(lsum, 32, 64);
        float linv[4];
        #pragma unroll
        for (int r = 0; r < 4; r++)
            linv[r] = 1.f / __shfl(lsum, rgrp * 4 + r, 64);

        // epilogue: normalize, gate, store wa as bf16 [B,Q,H*HD]
        const bf16_t* gptr = gateb + (size_t)(b * Hn + h) * Qn * HDn;
        bf16_t* wptr = wab + (size_t)b * Qn * 256;
        const int qg = q0 + rgrp * 4;
        #pragma unroll
        for (int nt = 0; nt < 2; nt++) {
            int d = nt * 16 + c15;
            #pragma unroll
            for (int r = 0; r < 4; r++) {
                float g = (float)gptr[(qg + r) * HDn + d];
                wptr[(qg + r) * 256 + h * 32 + d] = tob(o[nt][r] * linv[r] * g);
            }
        }
    }
}

// ---------------- output projection + bias ----------------
__global__ __launch_bounds__(256) void outproj_kernel(
    const bf16_t* __restrict__ wab, const bf16_t* __restrict__ wto,
    const float* __restrict__ outb, float* __restrict__ out)
{
    __shared__ bf16_t alds[64 * ALDS_STRIDE];
    const int m0 = blockIdx.x * 64;
    const int tid = threadIdx.x;
    const int lane = tid & 63;
    const int w = tid >> 6;
    const int ncb = w * 64;
    const int c15 = lane & 15;
    const int rgrp = lane >> 4;
    const int kof = rgrp * 8;

    #pragma unroll
    for (int i = 0; i < 8; i++) {
        int u = tid + i * 256;
        int row = u >> 5;
        int c16 = u & 31;
        bf16x8 a8 = *reinterpret_cast<const bf16x8*>(wab + (size_t)(m0 + row) * 256 + c16 * 8);
        *reinterpret_cast<bf16x8*>(&alds[row * ALDS_STRIDE + c16 * 8]) = a8;
    }
    __syncthreads();

    f32x4 acc[4][4] = {};
    #pragma unroll
    for (int kc = 0; kc < 8; kc++) {
        bf16x8 am[4], bn[4];
        #pragma unroll
        for (int i = 0; i < 4; i++)
            am[i] = *reinterpret_cast<const bf16x8*>(&alds[(i * 16 + c15) * ALDS_STRIDE + kc * 32 + kof]);
        #pragma unroll
        for (int j = 0; j < 4; j++)
            bn[j] = *reinterpret_cast<const bf16x8*>(wto + (ncb + j * 16 + c15) * 256 + kc * 32 + kof);
        #pragma unroll
        for (int i = 0; i < 4; i++)
            #pragma unroll
            for (int j = 0; j < 4; j++)
                acc[i][j] = __builtin_amdgcn_mfma_f32_16x16x32_bf16(am[i], bn[j], acc[i][j], 0, 0, 0);
    }

    #pragma unroll
    for (int j = 0; j < 4; j++) {
        int n = ncb + j * 16 + c15;
        float ob = outb[n];
        #pragma unroll
        for (int i = 0; i < 4; i++) {
            #pragma unroll
            for (int r = 0; r < 4; r++) {
                int m = m0 + i * 16 + rgrp * 4 + r;
                out[(size_t)m * 256 + n] = acc[i][j][r] + ob;
            }
        }
    }
}

extern "C" void kernel_launch(void* const* d_in, const int* in_sizes, int n_in,
                              void* d_out, int out_size, void* d_ws, size_t ws_size,
                              hipStream_t stream) {
    const float* q_data = (const float*)d_in[0];
    const float* m_data = (const float*)d_in[1];
    const float* bias = (const float*)d_in[2];
    const float* nbias = (const float*)d_in[3];
    const float* query_w = (const float*)d_in[4];
    const float* key_w = (const float*)d_in[5];
    const float* value_w = (const float*)d_in[6];
    const float* gating_w = (const float*)d_in[7];
    const float* gating_b = (const float*)d_in[8];
    const float* output_w = (const float*)d_in[9];
    const float* output_b = (const float*)d_in[10];
    float* out = (float*)d_out;

    char* ws = (char*)d_ws;
    const size_t WT = 256 * 256 * sizeof(bf16_t);
    const size_t PROJ = (size_t)Bb * Hn * Qn * HDn;
    bf16_t* wtq = (bf16_t*)(ws);
    bf16_t* wtk = (bf16_t*)(ws + WT);
    bf16_t* wtv = (bf16_t*)(ws + 2 * WT);
    bf16_t* wtg = (bf16_t*)(ws + 3 * WT);
    bf16_t* wto = (bf16_t*)(ws + 4 * WT);
    bf16_t* qb = (bf16_t*)(ws + 5 * WT);
    bf16_t* kb = qb + PROJ;
    bf16_t* vtb = kb + PROJ;
    bf16_t* gateb = vtb + PROJ;
    bf16_t* wab = gateb + PROJ;

    prep_weights<<<1280, 256, 0, stream>>>(query_w, key_w, value_w, gating_w, output_w,
                                           wtq, wtk, wtv, wtg, wto);
    proj_kernel<<<dim3(512, 2), 512, 0, stream>>>(q_data, m_data, wtq, wtk, wtv, wtg,
                                                  gating_b, qb, kb, vtb, gateb);
    attn_kernel<<<512, 256, 0, stream>>>(qb, kb, vtb, gateb, bias, nbias, wab);
    outproj_kernel<<<512, 256, 0, stream>>>(wab, wto, output_b, out);
}

// Round 8
// 184.386 us; speedup vs baseline: 1.2488x; 1.2488x over previous
//
#include <hip/hip_runtime.h>
#include <math.h>

#define Bb 64
#define Qn 512
#define Kn 512
#define Cn 256
#define Hn 8
#define HDn 32
#define OUTn 256

typedef __bf16 bf16_t;
typedef __attribute__((ext_vector_type(4))) __bf16 bf16x4;
typedef __attribute__((ext_vector_type(8))) __bf16 bf16x8;
typedef __attribute__((ext_vector_type(4))) float f32x4;
typedef __attribute__((ext_vector_type(4))) unsigned int u32x4;

__device__ inline bf16_t tob(float f) {
    unsigned int u = __float_as_uint(f);
    u += 0x7fff + ((u >> 16) & 1);   // RNE
    unsigned short s = (unsigned short)(u >> 16);
    return __builtin_bit_cast(bf16_t, s);
}

// async global->LDS, 16B per lane; LDS dest = wave-uniform base + lane*16
__device__ inline void gl_lds16(const void* g, void* l) {
    __builtin_amdgcn_global_load_lds(
        (const __attribute__((address_space(1))) unsigned int*)g,
        (__attribute__((address_space(3))) unsigned int*)l, 16, 0, 0);
}

// ---------------- weight prep: transpose + cast to bf16 ----------------
__global__ __launch_bounds__(256) void prep_weights(
    const float* __restrict__ qw, const float* __restrict__ kw,
    const float* __restrict__ vw, const float* __restrict__ gw,
    const float* __restrict__ ow,
    bf16_t* __restrict__ wtq, bf16_t* __restrict__ wtk,
    bf16_t* __restrict__ wtv, bf16_t* __restrict__ wtg,
    bf16_t* __restrict__ wto)
{
    int tid = blockIdx.x * 256 + threadIdx.x;   // 0 .. 5*65536-1
    int mat = tid >> 16;
    int rem = tid & 65535;
    int a = rem >> 8;    // source row (k dim)
    int n = rem & 255;   // source col (n dim)
    const float* src = mat == 0 ? qw : mat == 1 ? kw : mat == 2 ? vw : mat == 3 ? gw : ow;
    bf16_t* dst = mat == 0 ? wtq : mat == 1 ? wtk : mat == 2 ? wtv : mat == 3 ? wtg : wto;
    dst[n * 256 + a] = tob(src[a * 256 + n]);
}

// ---------------- bias tiling: rearrange to MFMA-fragment layout ----------
// btile[b][q16][c][t][lane][r] = bias[b][q16*16+(lane&15)][c*64+t*16+(lane>>4)*4+r]
// ntile[h][q16][c][t][lane][r] = nbias[h][same][same]
// Writes fully coalesced; reads are 16 rows x 64B per wave (100% line use).
__global__ __launch_bounds__(256) void prep_bias(
    const float* __restrict__ bias, const float* __restrict__ nbias,
    float* __restrict__ btile, float* __restrict__ ntile)
{
    size_t vid = (size_t)blockIdx.x * 256 + threadIdx.x;   // one f32x4 each
    const size_t NB = (size_t)64 * 65536;                  // bias vec4 count
    int lane, t, c, q16;
    if (vid < NB) {
        lane = vid & 63; t = (vid >> 6) & 3; c = (vid >> 8) & 7; q16 = (vid >> 11) & 31;
        int b = vid >> 16;
        int row = q16 * 16 + (lane & 15);
        int col = c * 64 + t * 16 + (lane >> 4) * 4;
        f32x4 v = *reinterpret_cast<const f32x4*>(bias + ((size_t)b * Qn + row) * Kn + col);
        *reinterpret_cast<f32x4*>(btile + vid * 4) = v;
    } else {
        size_t nv = vid - NB;                              // 8*65536 vec4
        lane = nv & 63; t = (nv >> 6) & 3; c = (nv >> 8) & 7; q16 = (nv >> 11) & 31;
        int h = nv >> 16;
        int row = q16 * 16 + (lane & 15);
        int col = c * 64 + t * 16 + (lane >> 4) * 4;
        f32x4 v = *reinterpret_cast<const f32x4*>(nbias + ((size_t)h * Qn + row) * Kn + col);
        *reinterpret_cast<f32x4*>(ntile + nv * 4) = v;
    }
}

// ---------------- projections ----------------
// v is stored with a permuted k-axis so attention's PV step can consume P
// directly from the QK^T accumulator layout (no LDS transpose):
//   vbuf[d][kk] = V[pos][d],  kk = perm^-1(pos),
//   perm^-1 on low 5 bits: kk = p3<<4 | p2<<3 | p4<<2 | p1<<1 | p0.
#define ALDS_STRIDE 264   // 256 + 8 pad
__global__ __launch_bounds__(512) void proj_kernel(
    const float* __restrict__ qdata, const float* __restrict__ mdata,
    const bf16_t* __restrict__ wtq, const bf16_t* __restrict__ wtk,
    const bf16_t* __restrict__ wtv, const bf16_t* __restrict__ wtg,
    const float* __restrict__ gating_b,
    bf16_t* __restrict__ qb, bf16_t* __restrict__ kb,
    bf16_t* __restrict__ vTb, bf16_t* __restrict__ gateb)
{
    __shared__ bf16_t alds[64 * ALDS_STRIDE];
    const int side = blockIdx.y;          // 0: q_data, 1: m_data
    const int m0 = blockIdx.x * 64;
    const int tid = threadIdx.x;
    const int lane = tid & 63;
    const int w = tid >> 6;               // wave 0..7
    const int ch = w >> 2;                // 0: q|k, 1: gate|v
    const int ncb = (w & 3) * 64;
    const int c15 = lane & 15;
    const int rgrp = lane >> 4;
    const int kof = rgrp * 8;
    const float* X = side ? mdata : qdata;
    const bf16_t* Wt = side == 0 ? (ch == 0 ? wtq : wtg) : (ch == 0 ? wtk : wtv);
    const bool vout = (side == 1) && (ch == 1);

    #pragma unroll
    for (int i = 0; i < 8; i++) {
        int u = tid + i * 512;            // 4096 f32x4 units
        int row = u >> 6;
        int c4 = u & 63;
        f32x4 a4 = *reinterpret_cast<const f32x4*>(X + (size_t)(m0 + row) * 256 + c4 * 4);
        bf16_t* dst = &alds[row * ALDS_STRIDE + c4 * 4];
        #pragma unroll
        for (int j = 0; j < 4; j++) dst[j] = tob(a4[j]);
    }
    __syncthreads();

    f32x4 acc[4][4] = {};
    #pragma unroll
    for (int kc = 0; kc < 8; kc++) {
        bf16x8 am[4], bn[4];
        #pragma unroll
        for (int i = 0; i < 4; i++)
            am[i] = *reinterpret_cast<const bf16x8*>(&alds[(i * 16 + c15) * ALDS_STRIDE + kc * 32 + kof]);
        #pragma unroll
        for (int j = 0; j < 4; j++)
            bn[j] = *reinterpret_cast<const bf16x8*>(Wt + (ncb + j * 16 + c15) * 256 + kc * 32 + kof);
        #pragma unroll
        for (int i = 0; i < 4; i++)
            #pragma unroll
            for (int j = 0; j < 4; j++) {
                if (vout)
                    acc[i][j] = __builtin_amdgcn_mfma_f32_16x16x32_bf16(bn[j], am[i], acc[i][j], 0, 0, 0);
                else
                    acc[i][j] = __builtin_amdgcn_mfma_f32_16x16x32_bf16(am[i], bn[j], acc[i][j], 0, 0, 0);
            }
    }

    // q is pre-scaled by log2(e)/sqrt(32): softmax computes exp2 directly.
    const float scale = 0.17677669529663687f * 1.4426950408889634f;
    if (!vout) {
        #pragma unroll
        for (int j = 0; j < 4; j++) {
            int n = ncb + j * 16 + c15;
            int h = n >> 5, d = n & 31;
            #pragma unroll
            for (int i = 0; i < 4; i++) {
                #pragma unroll
                for (int r = 0; r < 4; r++) {
                    int m = m0 + i * 16 + rgrp * 4 + r;
                    int b = m >> 9, pos = m & 511;
                    float v = acc[i][j][r];
                    size_t idx = (((size_t)(b * Hn + h) * Qn + pos) << 5) + d;
                    if (side == 0) {
                        if (ch == 0) {
                            qb[idx] = tob(v * scale);
                        } else {
                            float g = 1.f / (1.f + __expf(-(v + gating_b[n])));
                            gateb[idx] = tob(g);
                        }
                    } else {
                        kb[idx] = tob(v);
                    }
                }
            }
        }
    } else {
        // transposed acc: lanes index m-rows (key positions), regs index n=(h,d)
        #pragma unroll
        for (int i = 0; i < 4; i++) {
            int m = m0 + i * 16 + c15;
            int b = m >> 9, pos = m & 511;
            int kk = (pos & ~31) | (((pos >> 3) & 1) << 4) | (((pos >> 2) & 1) << 3)
                   | (((pos >> 4) & 1) << 2) | (pos & 3);
            #pragma unroll
            for (int j = 0; j < 4; j++) {
                #pragma unroll
                for (int r = 0; r < 4; r++) {
                    int n = ncb + j * 16 + rgrp * 4 + r;
                    int h = n >> 5, d = n & 31;
                    vTb[((size_t)(b * Hn + h) * HDn + d) * Kn + kk] = tob(acc[i][j][r]);
                }
            }
        }
    }
}

// ---------------- fused attention, TILED-BIAS variant ---------------------
// R8: bias/nbias pre-tiled to fragment layout (prep_bias) -> per chunk,
// 8 perfectly-coalesced dwordx4 loads straight to registers. The bias LDS
// (16KB), its write/fence/read round-trip, and the transpose are GONE.
// LDS = 16KB kv dbuf only -> occupancy cap rises to wave-slot limit
// (32/CU). R6->R7 A/B proved the kernel is latency-bound and responds to
// waves/CU (14->7 waves = 126->176us), not to FETCH (196->98MB = no gain):
// TLP is the lever.
// Counted vmcnt (T4): at the wait, outstanding = stage(c)[2 oldest] +
// bias(c)[8 newer] -> vmcnt(8) drains exactly stage(c); compiler inserts
// vmcnt(2) before the bias adds, keeping stage(c+1) in flight.
__global__ __launch_bounds__(256) void attn_kernel(
    const bf16_t* __restrict__ qb, const bf16_t* __restrict__ kb,
    const bf16_t* __restrict__ vTb, const bf16_t* __restrict__ gateb,
    const float* __restrict__ btile, const float* __restrict__ ntile,
    bf16_t* __restrict__ wab)
{
    __shared__ __align__(16) char kvlds[2][8192];    // [buf][K 4KB | V 4KB]
    const int p = blockIdx.x;
    const int qt = p & 7;
    const int h = (p >> 3) & 7;
    const int b = p >> 6;
    const int lane = threadIdx.x & 63;
    const int wv = threadIdx.x >> 6;
    const int q0 = qt * 64 + wv * 16;
    const int q16 = qt * 4 + wv;
    const int c15 = lane & 15;
    const int rgrp = lane >> 4;
    const int kof = rgrp * 8;

    const bf16_t* qbase = qb + (size_t)(b * Hn + h) * Qn * HDn;
    const bf16_t* kbase = kb + (size_t)(b * Hn + h) * Kn * HDn;
    const bf16_t* vbase = vTb + (size_t)(b * Hn + h) * HDn * Kn;
    const float* btb = btile + (((size_t)b * 32 + q16) << 13) + lane * 4;   // 8192 f/q16
    const float* ntb = ntile + (((size_t)h * 32 + q16) << 13) + lane * 4;

    // staging lane geometry (constant per thread)
    const int krw = (wv << 4) + (lane >> 2);        // K row 0..63
    const int kcb = (lane & 3) << 4;                // K col byte
    const int vrw = (wv << 3) + (lane >> 3);        // V row 0..31
    const int vcb = (lane & 7) << 4;                // V col byte
    const size_t ksrc0 = ((size_t)krw << 6) + (size_t)(kcb ^ ((krw & 3) << 4));
    const size_t vsrc0 = ((size_t)vrw << 10) + (size_t)(vcb ^ ((vrw & 7) << 4));

    bf16x8 aq = *reinterpret_cast<const bf16x8*>(qbase + (q0 + c15) * HDn + kof);

    const float NML = -12.f * 1.4426950408889634f;   // -M*log2e, folded into QK^T C
    const float LOG2E = 1.4426950408889634f;
    const f32x4 zML = {NML, NML, NML, NML};
    f32x4 o[2] = {};
    f32x4 lsv = {0.f, 0.f, 0.f, 0.f};

    // ---- prologue: stage chunk 0 -> LDS buf 0 ----
    gl_lds16((const char*)kbase + ksrc0, (char*)kvlds[0] + wv * 1024);
    gl_lds16((const char*)vbase + vsrc0, (char*)kvlds[0] + 4096 + wv * 1024);

    #pragma unroll 1
    for (int c = 0; c < 8; c++) {         // 8 chunks of 64 k-cols
        const int pb = c & 1;
        // ---- bias/nbias tiled loads: 8 coalesced dwordx4 (newest VMEM) ----
        f32x4 bt[4], nt_[4];
        #pragma unroll
        for (int t = 0; t < 4; t++) {
            bt[t]  = *reinterpret_cast<const f32x4*>(btb + c * 1024 + t * 256);
            nt_[t] = *reinterpret_cast<const f32x4*>(ntb + c * 1024 + t * 256);
        }
        // ---- counted drain: kill stage(c) [2 oldest], keep bias [8] ----
        __builtin_amdgcn_sched_barrier(0);
        asm volatile("s_waitcnt vmcnt(8)" ::: "memory");
        __builtin_amdgcn_s_barrier();
        __builtin_amdgcn_sched_barrier(0);
        // ---- issue stage(c+1) into the other buffer (safe: post-barrier) --
        if (c < 7) {
            char* dstb = (char*)kvlds[pb ^ 1] + wv * 1024;
            gl_lds16((const char*)kbase + (size_t)((c + 1) << 12) + ksrc0, dstb);
            gl_lds16((const char*)vbase + (size_t)((c + 1) << 7) + vsrc0, dstb + 4096);
        }
        // ---- QK^T from LDS K tile (swizzled read) ----
        const char* kl = (const char*)kvlds[pb];
        f32x4 sc[4];
        #pragma unroll
        for (int t = 0; t < 4; t++) {
            int kr = t * 16 + c15;
            bf16x8 kf = *reinterpret_cast<const bf16x8*>(kl + (kr << 6) + ((rgrp << 4) ^ ((kr & 3) << 4)));
            sc[t] = __builtin_amdgcn_mfma_f32_16x16x32_bf16(kf, aq, zML, 0, 0, 0);
        }
        // ---- softmax: e = exp2(fma(bb, L, sc)); pack P via cvt_pk ----
        f32x4 es[4];
        #pragma unroll
        for (int t = 0; t < 4; t++) {
            f32x4 bb = bt[t] + nt_[t];
            #pragma unroll
            for (int r = 0; r < 4; r++)
                es[t][r] = __builtin_amdgcn_exp2f(fmaf(bb[r], LOG2E, sc[t][r]));
            lsv += es[t];
        }
        unsigned int pw[8];
        #pragma unroll
        for (int t = 0; t < 4; t++) {
            asm("v_cvt_pk_bf16_f32 %0, %1, %2" : "=v"(pw[t * 2 + 0]) : "v"(es[t][0]), "v"(es[t][1]));
            asm("v_cvt_pk_bf16_f32 %0, %1, %2" : "=v"(pw[t * 2 + 1]) : "v"(es[t][2]), "v"(es[t][3]));
        }
        u32x4 a0 = {pw[0], pw[1], pw[2], pw[3]};
        u32x4 a1 = {pw[4], pw[5], pw[6], pw[7]};
        bf16x8 pa0 = __builtin_bit_cast(bf16x8, a0);
        bf16x8 pa1 = __builtin_bit_cast(bf16x8, a1);
        // ---- PV from LDS V tile (swizzled read), P in-register ----
        #pragma unroll
        for (int sub = 0; sub < 2; sub++) {
            bf16x8 ap = sub == 0 ? pa0 : pa1;
            #pragma unroll
            for (int nt = 0; nt < 2; nt++) {
                int vr = nt * 16 + c15;
                bf16x8 bv = *reinterpret_cast<const bf16x8*>(kl + 4096 + (vr << 7)
                                + (((sub << 6) | (rgrp << 4)) ^ ((vr & 7) << 4)));
                o[nt] = __builtin_amdgcn_mfma_f32_16x16x32_bf16(ap, bv, o[nt], 0, 0, 0);
            }
        }
    }

    float lsum = (lsv[0] + lsv[1]) + (lsv[2] + lsv[3]);
    lsum += __shfl_xor(lsum, 16, 64);
    lsum += __shfl_xor(lsum, 32, 64);
    float linv[4];
    #pragma unroll
    for (int r = 0; r < 4; r++)
        linv[r] = 1.f / __shfl(lsum, rgrp * 4 + r, 64);

    // epilogue: normalize, gate, store wa as bf16 [B,Q,H*HD]
    const bf16_t* gptr = gateb + (size_t)(b * Hn + h) * Qn * HDn;
    bf16_t* wptr = wab + (size_t)b * Qn * 256;
    const int qg = q0 + rgrp * 4;
    #pragma unroll
    for (int nt = 0; nt < 2; nt++) {
        int d = nt * 16 + c15;
        #pragma unroll
        for (int r = 0; r < 4; r++) {
            float g = (float)gptr[(qg + r) * HDn + d];
            wptr[(qg + r) * 256 + h * 32 + d] = tob(o[nt][r] * linv[r] * g);
        }
    }
}

// ---------------- fused attention, FALLBACK (R6 verbatim) -----------------
// Used only if ws_size can't hold the 75MB bias tiles. Measured 126us.
__global__ __launch_bounds__(256) void attn_kernel_fb(
    const bf16_t* __restrict__ qb, const bf16_t* __restrict__ kb,
    const bf16_t* __restrict__ vTb, const bf16_t* __restrict__ gateb,
    const float* __restrict__ bias, const float* __restrict__ nbias,
    bf16_t* __restrict__ wab)
{
    __shared__ __align__(16) char kvlds[2][8192];
    __shared__ __align__(16) float blds[4][16 * 64];
    const int p = blockIdx.x;
    const int qt = p & 7;
    const int h = (p >> 3) & 7;
    const int b = p >> 6;
    const int lane = threadIdx.x & 63;
    const int wv = threadIdx.x >> 6;
    const int q0 = qt * 64 + wv * 16;
    const int c15 = lane & 15;
    const int rgrp = lane >> 4;
    const int kof = rgrp * 8;

    const bf16_t* qbase = qb + (size_t)(b * Hn + h) * Qn * HDn;
    const bf16_t* kbase = kb + (size_t)(b * Hn + h) * Kn * HDn;
    const bf16_t* vbase = vTb + (size_t)(b * Hn + h) * HDn * Kn;
    const float* bROW = bias + ((size_t)b * Qn + q0) * Kn;
    const float* nROW = nbias + ((size_t)h * Qn + q0) * Kn;
    char* blw = (char*)blds[wv];

    const int krw = (wv << 4) + (lane >> 2);
    const int kcb = (lane & 3) << 4;
    const int vrw = (wv << 3) + (lane >> 3);
    const int vcb = (lane & 7) << 4;
    const size_t ksrc0 = ((size_t)krw << 6) + (size_t)(kcb ^ ((krw & 3) << 4));
    const size_t vsrc0 = ((size_t)vrw << 10) + (size_t)(vcb ^ ((vrw & 7) << 4));

    bf16x8 aq = *reinterpret_cast<const bf16x8*>(qbase + (q0 + c15) * HDn + kof);

    const float LOG2E = 1.4426950408889634f;
    const float NML = -12.f * 1.4426950408889634f;
    const f32x4 zML = {NML, NML, NML, NML};
    f32x4 o[2] = {};
    f32x4 lsv = {0.f, 0.f, 0.f, 0.f};

    f32x4 bs[4];
    #pragma unroll
    for (int u = 0; u < 4; u++) {
        int row = u * 4 + rgrp;
        f32x4 x = *reinterpret_cast<const f32x4*>(bROW + (size_t)row * Kn + c15 * 4);
        f32x4 y = *reinterpret_cast<const f32x4*>(nROW + (size_t)row * Kn + c15 * 4);
        bs[u] = x + y;
    }
    gl_lds16((const char*)kbase + ksrc0, (char*)kvlds[0] + wv * 1024);
    gl_lds16((const char*)vbase + vsrc0, (char*)kvlds[0] + 4096 + wv * 1024);

    #pragma unroll 1
    for (int c = 0; c < 8; c++) {
        const int pb = c & 1;
        #pragma unroll
        for (int u = 0; u < 4; u++) {
            int row = u * 4 + rgrp;
            *reinterpret_cast<f32x4*>(blw + (row << 8) + ((c15 << 4) ^ ((row & 7) << 4))) = bs[u];
        }
        if (c < 7) {
            #pragma unroll
            for (int u = 0; u < 4; u++) {
                int row = u * 4 + rgrp;
                f32x4 x = *reinterpret_cast<const f32x4*>(bROW + (size_t)row * Kn + (c + 1) * 64 + c15 * 4);
                f32x4 y = *reinterpret_cast<const f32x4*>(nROW + (size_t)row * Kn + (c + 1) * 64 + c15 * 4);
                bs[u] = x + y;
            }
        }
        __builtin_amdgcn_sched_barrier(0);
        if (c < 7) asm volatile("s_waitcnt vmcnt(8)" ::: "memory");
        else       asm volatile("s_waitcnt vmcnt(0)" ::: "memory");
        __builtin_amdgcn_s_barrier();
        __builtin_amdgcn_sched_barrier(0);
        if (c < 7) {
            char* dstb = (char*)kvlds[pb ^ 1] + wv * 1024;
            gl_lds16((const char*)kbase + (size_t)((c + 1) << 12) + ksrc0, dstb);
            gl_lds16((const char*)vbase + (size_t)((c + 1) << 7) + vsrc0, dstb + 4096);
        }
        const char* kl = (const char*)kvlds[pb];
        f32x4 sc[4];
        #pragma unroll
        for (int t = 0; t < 4; t++) {
            int kr = t * 16 + c15;
            bf16x8 kf = *reinterpret_cast<const bf16x8*>(kl + (kr << 6) + ((rgrp << 4) ^ ((kr & 3) << 4)));
            sc[t] = __builtin_amdgcn_mfma_f32_16x16x32_bf16(kf, aq, zML, 0, 0, 0);
        }
        f32x4 es[4];
        #pragma unroll
        for (int t = 0; t < 4; t++) {
            f32x4 bb = *reinterpret_cast<const f32x4*>(blw + (c15 << 8) + (((t << 6) | (rgrp << 4)) ^ ((c15 & 7) << 4)));
            #pragma unroll
            for (int r = 0; r < 4; r++)
                es[t][r] = __builtin_amdgcn_exp2f(fmaf(bb[r], LOG2E, sc[t][r]));
            lsv += es[t];
        }
        unsigned int pw[8];
        #pragma unroll
        for (int t = 0; t < 4; t++) {
            asm("v_cvt_pk_bf16_f32 %0, %1, %2" : "=v"(pw[t * 2 + 0]) : "v"(es[t][0]), "v"(es[t][1]));
            asm("v_cvt_pk_bf16_f32 %0, %1, %2" : "=v"(pw[t * 2 + 1]) : "v"(es[t][2]), "v"(es[t][3]));
        }
        u32x4 a0 = {pw[0], pw[1], pw[2], pw[3]};
        u32x4 a1 = {pw[4], pw[5], pw[6], pw[7]};
        bf16x8 pa0 = __builtin_bit_cast(bf16x8, a0);
        bf16x8 pa1 = __builtin_bit_cast(bf16x8, a1);
        #pragma unroll
        for (int sub = 0; sub < 2; sub++) {
            bf16x8 ap = sub == 0 ? pa0 : pa1;
            #pragma unroll
            for (int nt = 0; nt < 2; nt++) {
                int vr = nt * 16 + c15;
                bf16x8 bv = *reinterpret_cast<const bf16x8*>(kl + 4096 + (vr << 7)
                                + (((sub << 6) | (rgrp << 4)) ^ ((vr & 7) << 4)));
                o[nt] = __builtin_amdgcn_mfma_f32_16x16x32_bf16(ap, bv, o[nt], 0, 0, 0);
            }
        }
    }

    float lsum = (lsv[0] + lsv[1]) + (lsv[2] + lsv[3]);
    lsum += __shfl_xor(lsum, 16, 64);
    lsum += __shfl_xor(lsum, 32, 64);
    float linv[4];
    #pragma unroll
    for (int r = 0; r < 4; r++)
        linv[r] = 1.f / __shfl(lsum, rgrp * 4 + r, 64);

    const bf16_t* gptr = gateb + (size_t)(b * Hn + h) * Qn * HDn;
    bf16_t* wptr = wab + (size_t)b * Qn * 256;
    const int qg = q0 + rgrp * 4;
    #pragma unroll
    for (int nt = 0; nt < 2; nt++) {
        int d = nt * 16 + c15;
        #pragma unroll
        for (int r = 0; r < 4; r++) {
            float g = (float)gptr[(qg + r) * HDn + d];
            wptr[(qg + r) * 256 + h * 32 + d] = tob(o[nt][r] * linv[r] * g);
        }
    }
}

// ---------------- output projection + bias ----------------
__global__ __launch_bounds__(256) void outproj_kernel(
    const bf16_t* __restrict__ wab, const bf16_t* __restrict__ wto,
    const float* __restrict__ outb, float* __restrict__ out)
{
    __shared__ bf16_t alds[64 * ALDS_STRIDE];
    const int m0 = blockIdx.x * 64;
    const int tid = threadIdx.x;
    const int lane = tid & 63;
    const int w = tid >> 6;
    const int ncb = w * 64;
    const int c15 = lane & 15;
    const int rgrp = lane >> 4;
    const int kof = rgrp * 8;

    #pragma unroll
    for (int i = 0; i < 8; i++) {
        int u = tid + i * 256;
        int row = u >> 5;
        int c16 = u & 31;
        bf16x8 a8 = *reinterpret_cast<const bf16x8*>(wab + (size_t)(m0 + row) * 256 + c16 * 8);
        *reinterpret_cast<bf16x8*>(&alds[row * ALDS_STRIDE + c16 * 8]) = a8;
    }
    __syncthreads();

    f32x4 acc[4][4] = {};
    #pragma unroll
    for (int kc = 0; kc < 8; kc++) {
        bf16x8 am[4], bn[4];
        #pragma unroll
        for (int i = 0; i < 4; i++)
            am[i] = *reinterpret_cast<const bf16x8*>(&alds[(i * 16 + c15) * ALDS_STRIDE + kc * 32 + kof]);
        #pragma unroll
        for (int j = 0; j < 4; j++)
            bn[j] = *reinterpret_cast<const bf16x8*>(wto + (ncb + j * 16 + c15) * 256 + kc * 32 + kof);
        #pragma unroll
        for (int i = 0; i < 4; i++)
            #pragma unroll
            for (int j = 0; j < 4; j++)
                acc[i][j] = __builtin_amdgcn_mfma_f32_16x16x32_bf16(am[i], bn[j], acc[i][j], 0, 0, 0);
    }

    #pragma unroll
    for (int j = 0; j < 4; j++) {
        int n = ncb + j * 16 + c15;
        float ob = outb[n];
        #pragma unroll
        for (int i = 0; i < 4; i++) {
            #pragma unroll
            for (int r = 0; r < 4; r++) {
                int m = m0 + i * 16 + rgrp * 4 + r;
                out[(size_t)m * 256 + n] = acc[i][j][r] + ob;
            }
        }
    }
}

extern "C" void kernel_launch(void* const* d_in, const int* in_sizes, int n_in,
                              void* d_out, int out_size, void* d_ws, size_t ws_size,
                              hipStream_t stream) {
    const float* q_data = (const float*)d_in[0];
    const float* m_data = (const float*)d_in[1];
    const float* bias = (const float*)d_in[2];
    const float* nbias = (const float*)d_in[3];
    const float* query_w = (const float*)d_in[4];
    const float* key_w = (const float*)d_in[5];
    const float* value_w = (const float*)d_in[6];
    const float* gating_w = (const float*)d_in[7];
    const float* gating_b = (const float*)d_in[8];
    const float* output_w = (const float*)d_in[9];
    const float* output_b = (const float*)d_in[10];
    float* out = (float*)d_out;

    char* ws = (char*)d_ws;
    const size_t WT = 256 * 256 * sizeof(bf16_t);
    const size_t PROJ = (size_t)Bb * Hn * Qn * HDn;      // bf16 elems
    bf16_t* wtq = (bf16_t*)(ws);
    bf16_t* wtk = (bf16_t*)(ws + WT);
    bf16_t* wtv = (bf16_t*)(ws + 2 * WT);
    bf16_t* wtg = (bf16_t*)(ws + 3 * WT);
    bf16_t* wto = (bf16_t*)(ws + 4 * WT);
    bf16_t* qb = (bf16_t*)(ws + 5 * WT);
    bf16_t* kb = qb + PROJ;
    bf16_t* vtb = kb + PROJ;
    bf16_t* gateb = vtb + PROJ;
    bf16_t* wab = gateb + PROJ;

    const size_t BASE = 5 * WT + 5 * PROJ * sizeof(bf16_t);
    const size_t BT_BYTES = (size_t)64 * 65536 * 16;     // 67.1 MB
    const size_t NT_BYTES = (size_t)8 * 65536 * 16;      // 8.4 MB
    const size_t NEED = BASE + BT_BYTES + NT_BYTES;

    prep_weights<<<1280, 256, 0, stream>>>(query_w, key_w, value_w, gating_w, output_w,
                                           wtq, wtk, wtv, wtg, wto);
    proj_kernel<<<dim3(512, 2), 512, 0, stream>>>(q_data, m_data, wtq, wtk, wtv, wtg,
                                                  gating_b, qb, kb, vtb, gateb);
    if (ws_size >= NEED) {
        float* btile = (float*)(ws + BASE);
        float* ntile = (float*)(ws + BASE + BT_BYTES);
        prep_bias<<<18432, 256, 0, stream>>>(bias, nbias, btile, ntile);
        attn_kernel<<<4096, 256, 0, stream>>>(qb, kb, vtb, gateb, btile, ntile, wab);
    } else {
        attn_kernel_fb<<<4096, 256, 0, stream>>>(qb, kb, vtb, gateb, bias, nbias, wab);
    }
    outproj_kernel<<<512, 256, 0, stream>>>(wab, wto, output_b, out);
}

// Round 9
// 183.186 us; speedup vs baseline: 1.2570x; 1.0066x over previous
//
#include <hip/hip_runtime.h>
#include <math.h>

#define Bb 64
#define Qn 512
#define Kn 512
#define Cn 256
#define Hn 8
#define HDn 32
#define OUTn 256

typedef __bf16 bf16_t;
typedef __attribute__((ext_vector_type(4))) __bf16 bf16x4;
typedef __attribute__((ext_vector_type(8))) __bf16 bf16x8;
typedef __attribute__((ext_vector_type(4))) float f32x4;
typedef __attribute__((ext_vector_type(4))) unsigned int u32x4;

__device__ inline bf16_t tob(float f) {
    unsigned int u = __float_as_uint(f);
    u += 0x7fff + ((u >> 16) & 1);   // RNE
    unsigned short s = (unsigned short)(u >> 16);
    return __builtin_bit_cast(bf16_t, s);
}

// async global->LDS, 16B per lane; LDS dest = wave-uniform base + lane*16
__device__ inline void gl_lds16(const void* g, void* l) {
    __builtin_amdgcn_global_load_lds(
        (const __attribute__((address_space(1))) unsigned int*)g,
        (__attribute__((address_space(3))) unsigned int*)l, 16, 0, 0);
}

// ---------------- weight prep: transpose + cast to bf16 ----------------
__global__ __launch_bounds__(256) void prep_weights(
    const float* __restrict__ qw, const float* __restrict__ kw,
    const float* __restrict__ vw, const float* __restrict__ gw,
    const float* __restrict__ ow,
    bf16_t* __restrict__ wtq, bf16_t* __restrict__ wtk,
    bf16_t* __restrict__ wtv, bf16_t* __restrict__ wtg,
    bf16_t* __restrict__ wto)
{
    int tid = blockIdx.x * 256 + threadIdx.x;   // 0 .. 5*65536-1
    int mat = tid >> 16;
    int rem = tid & 65535;
    int a = rem >> 8;    // source row (k dim)
    int n = rem & 255;   // source col (n dim)
    const float* src = mat == 0 ? qw : mat == 1 ? kw : mat == 2 ? vw : mat == 3 ? gw : ow;
    bf16_t* dst = mat == 0 ? wtq : mat == 1 ? wtk : mat == 2 ? wtv : mat == 3 ? wtg : wto;
    dst[n * 256 + a] = tob(src[a * 256 + n]);
}

// ---------------- bias tiling: rearrange to MFMA-fragment layout ----------
// btile[b][q16][c][t][lane][r] = bias[b][q16*16+(lane&15)][c*64+t*16+(lane>>4)*4+r]
// ntile[h][q16][c][t][lane][r] = nbias[h][same][same]
__global__ __launch_bounds__(256) void prep_bias(
    const float* __restrict__ bias, const float* __restrict__ nbias,
    float* __restrict__ btile, float* __restrict__ ntile)
{
    size_t vid = (size_t)blockIdx.x * 256 + threadIdx.x;   // one f32x4 each
    const size_t NB = (size_t)64 * 65536;                  // bias vec4 count
    int lane, t, c, q16;
    if (vid < NB) {
        lane = vid & 63; t = (vid >> 6) & 3; c = (vid >> 8) & 7; q16 = (vid >> 11) & 31;
        int b = vid >> 16;
        int row = q16 * 16 + (lane & 15);
        int col = c * 64 + t * 16 + (lane >> 4) * 4;
        f32x4 v = *reinterpret_cast<const f32x4*>(bias + ((size_t)b * Qn + row) * Kn + col);
        *reinterpret_cast<f32x4*>(btile + vid * 4) = v;
    } else {
        size_t nv = vid - NB;                              // 8*65536 vec4
        lane = nv & 63; t = (nv >> 6) & 3; c = (nv >> 8) & 7; q16 = (nv >> 11) & 31;
        int h = nv >> 16;
        int row = q16 * 16 + (lane & 15);
        int col = c * 64 + t * 16 + (lane >> 4) * 4;
        f32x4 v = *reinterpret_cast<const f32x4*>(nbias + ((size_t)h * Qn + row) * Kn + col);
        *reinterpret_cast<f32x4*>(ntile + nv * 4) = v;
    }
}

// ---------------- projections ----------------
// v is stored with a permuted k-axis so attention's PV step can consume P
// directly from the QK^T accumulator layout (no LDS transpose):
//   vbuf[d][kk] = V[pos][d],  kk = perm^-1(pos),
//   perm^-1 on low 5 bits: kk = p3<<4 | p2<<3 | p4<<2 | p1<<1 | p0.
// R9: epilogue restaged through LDS -> fully coalesced 16B stores.
// R8 rocprof showed proj at 113us, 0.9 TB/s, with 64 scattered 2B global
// stores per thread (the vout path's bit-permuted kk = up to 64 segments
// per instr). Restage: wave writes its 64x64 tile to a private LDS slice
// (scalar ds_write_b16), reads back 16B/lane, stores full 64B lines.
// Strides 72 (!vout) / 40 (vout) keep every 16B LDS read aligned.
#define ALDS_STRIDE 264   // 256 + 8 pad
__global__ __launch_bounds__(512) void proj_kernel(
    const float* __restrict__ qdata, const float* __restrict__ mdata,
    const bf16_t* __restrict__ wtq, const bf16_t* __restrict__ wtk,
    const bf16_t* __restrict__ wtv, const bf16_t* __restrict__ wtg,
    const float* __restrict__ gating_b,
    bf16_t* __restrict__ qb, bf16_t* __restrict__ kb,
    bf16_t* __restrict__ vTb, bf16_t* __restrict__ gateb)
{
    __shared__ __align__(16) bf16_t smem[20480];   // A-tile (16896) / scratch (8x2560)
    bf16_t* alds = smem;
    const int side = blockIdx.y;          // 0: q_data, 1: m_data
    const int m0 = blockIdx.x * 64;
    const int tid = threadIdx.x;
    const int lane = tid & 63;
    const int w = tid >> 6;               // wave 0..7
    const int ch = w >> 2;                // 0: q|k, 1: gate|v
    const int ncb = (w & 3) * 64;
    const int c15 = lane & 15;
    const int rgrp = lane >> 4;
    const int kof = rgrp * 8;
    const float* X = side ? mdata : qdata;
    const bf16_t* Wt = side == 0 ? (ch == 0 ? wtq : wtg) : (ch == 0 ? wtk : wtv);
    const bool vout = (side == 1) && (ch == 1);

    #pragma unroll
    for (int i = 0; i < 8; i++) {
        int u = tid + i * 512;            // 4096 f32x4 units
        int row = u >> 6;
        int c4 = u & 63;
        f32x4 a4 = *reinterpret_cast<const f32x4*>(X + (size_t)(m0 + row) * 256 + c4 * 4);
        bf16_t* dst = &alds[row * ALDS_STRIDE + c4 * 4];
        #pragma unroll
        for (int j = 0; j < 4; j++) dst[j] = tob(a4[j]);
    }
    __syncthreads();

    f32x4 acc[4][4] = {};
    #pragma unroll
    for (int kc = 0; kc < 8; kc++) {
        bf16x8 am[4], bn[4];
        #pragma unroll
        for (int i = 0; i < 4; i++)
            am[i] = *reinterpret_cast<const bf16x8*>(&alds[(i * 16 + c15) * ALDS_STRIDE + kc * 32 + kof]);
        #pragma unroll
        for (int j = 0; j < 4; j++)
            bn[j] = *reinterpret_cast<const bf16x8*>(Wt + (ncb + j * 16 + c15) * 256 + kc * 32 + kof);
        #pragma unroll
        for (int i = 0; i < 4; i++)
            #pragma unroll
            for (int j = 0; j < 4; j++) {
                if (vout)
                    acc[i][j] = __builtin_amdgcn_mfma_f32_16x16x32_bf16(bn[j], am[i], acc[i][j], 0, 0, 0);
                else
                    acc[i][j] = __builtin_amdgcn_mfma_f32_16x16x32_bf16(am[i], bn[j], acc[i][j], 0, 0, 0);
            }
    }

    __syncthreads();                      // all alds A-tile reads done; reuse as scratch
    bf16_t* scr = smem + w * 2560;        // per-wave slice, 16B-aligned

    // q is pre-scaled by log2(e)/sqrt(32): softmax computes exp2 directly.
    const float scale = 0.17677669529663687f * 1.4426950408889634f;
    const int hbase = ncb >> 5;
    const int posbase = m0 & 511;
    const int b = m0 >> 9;

    if (!vout) {
        bf16_t* dst = side == 0 ? (ch == 0 ? qb : gateb) : kb;
        #pragma unroll
        for (int P = 0; P < 2; P++) {
            // stage 2 i-slices (32 rows x 64 cols) -> scr[row][col], stride 72
            #pragma unroll
            for (int ii = 0; ii < 2; ii++) {
                int i = P * 2 + ii;
                #pragma unroll
                for (int j = 0; j < 4; j++) {
                    int n = ncb + j * 16 + c15;
                    #pragma unroll
                    for (int r = 0; r < 4; r++) {
                        float v = acc[i][j][r];
                        if (side == 0) {
                            if (ch == 0) v *= scale;
                            else v = 1.f / (1.f + __expf(-(v + gating_b[n])));
                        }
                        scr[(ii * 16 + rgrp * 4 + r) * 72 + j * 16 + c15] = tob(v);
                    }
                }
            }
            asm volatile("" ::: "memory");
            // coalesced write-out: 4 iters x 16B/lane, full 64B lines/instr
            #pragma unroll
            for (int v2 = 0; v2 < 4; v2++) {
                int row = v2 * 8 + (lane >> 3);
                int col = (lane & 7) * 8;
                bf16x8 val = *reinterpret_cast<const bf16x8*>(&scr[row * 72 + col]);
                int pos = posbase + P * 32 + row;
                int hh = hbase + (col >> 5);
                int d = col & 31;
                *reinterpret_cast<bf16x8*>(dst + (((size_t)(b * Hn + hh) * Qn + pos) << 5) + d) = val;
            }
            asm volatile("" ::: "memory");   // pass1 writes after pass0 reads
        }
    } else {
        // transposed acc: lanes index m-rows (key positions), regs index n=(h,d)
        // kk perm folded into the LDS WRITE column; readback is stride-1 in kk.
        #pragma unroll
        for (int P = 0; P < 2; P++) {
            #pragma unroll
            for (int ii = 0; ii < 2; ii++) {
                int i = P * 2 + ii;
                int kperm = (((c15 >> 3) & 1) << 4) | (((c15 >> 2) & 1) << 3) | (ii << 2)
                          | (((c15 >> 1) & 1) << 1) | (c15 & 1);
                #pragma unroll
                for (int j = 0; j < 4; j++)
                    #pragma unroll
                    for (int r = 0; r < 4; r++)
                        scr[(j * 16 + rgrp * 4 + r) * 40 + kperm] = tob(acc[i][j][r]);
            }
            asm volatile("" ::: "memory");
            #pragma unroll
            for (int u = 0; u < 4; u++) {
                int nloc = u * 16 + (lane >> 2);
                int koff = (lane & 3) * 8;
                bf16x8 val = *reinterpret_cast<const bf16x8*>(&scr[nloc * 40 + koff]);
                int hh = hbase + (nloc >> 5);
                int d = nloc & 31;
                *reinterpret_cast<bf16x8*>(vTb + ((size_t)(b * Hn + hh) * HDn + d) * Kn
                                           + posbase + P * 32 + koff) = val;
            }
            asm volatile("" ::: "memory");
        }
    }
}

// ---------------- fused attention, TILED-BIAS (R8, unchanged) -------------
// bias/nbias pre-tiled to fragment layout -> 8 coalesced dwordx4 per chunk
// straight to registers. LDS = 16KB kv dbuf only. Counted vmcnt(8): at the
// wait, outstanding = stage(c)[2 oldest] + bias(c)[8 newer].
__global__ __launch_bounds__(256) void attn_kernel(
    const bf16_t* __restrict__ qb, const bf16_t* __restrict__ kb,
    const bf16_t* __restrict__ vTb, const bf16_t* __restrict__ gateb,
    const float* __restrict__ btile, const float* __restrict__ ntile,
    bf16_t* __restrict__ wab)
{
    __shared__ __align__(16) char kvlds[2][8192];    // [buf][K 4KB | V 4KB]
    const int p = blockIdx.x;
    const int qt = p & 7;
    const int h = (p >> 3) & 7;
    const int b = p >> 6;
    const int lane = threadIdx.x & 63;
    const int wv = threadIdx.x >> 6;
    const int q0 = qt * 64 + wv * 16;
    const int q16 = qt * 4 + wv;
    const int c15 = lane & 15;
    const int rgrp = lane >> 4;
    const int kof = rgrp * 8;

    const bf16_t* qbase = qb + (size_t)(b * Hn + h) * Qn * HDn;
    const bf16_t* kbase = kb + (size_t)(b * Hn + h) * Kn * HDn;
    const bf16_t* vbase = vTb + (size_t)(b * Hn + h) * HDn * Kn;
    const float* btb = btile + (((size_t)b * 32 + q16) << 13) + lane * 4;   // 8192 f/q16
    const float* ntb = ntile + (((size_t)h * 32 + q16) << 13) + lane * 4;

    // staging lane geometry (constant per thread)
    const int krw = (wv << 4) + (lane >> 2);        // K row 0..63
    const int kcb = (lane & 3) << 4;                // K col byte
    const int vrw = (wv << 3) + (lane >> 3);        // V row 0..31
    const int vcb = (lane & 7) << 4;                // V col byte
    const size_t ksrc0 = ((size_t)krw << 6) + (size_t)(kcb ^ ((krw & 3) << 4));
    const size_t vsrc0 = ((size_t)vrw << 10) + (size_t)(vcb ^ ((vrw & 7) << 4));

    bf16x8 aq = *reinterpret_cast<const bf16x8*>(qbase + (q0 + c15) * HDn + kof);

    const float NML = -12.f * 1.4426950408889634f;   // -M*log2e, folded into QK^T C
    const float LOG2E = 1.4426950408889634f;
    const f32x4 zML = {NML, NML, NML, NML};
    f32x4 o[2] = {};
    f32x4 lsv = {0.f, 0.f, 0.f, 0.f};

    // ---- prologue: stage chunk 0 -> LDS buf 0 ----
    gl_lds16((const char*)kbase + ksrc0, (char*)kvlds[0] + wv * 1024);
    gl_lds16((const char*)vbase + vsrc0, (char*)kvlds[0] + 4096 + wv * 1024);

    #pragma unroll 1
    for (int c = 0; c < 8; c++) {         // 8 chunks of 64 k-cols
        const int pb = c & 1;
        // ---- bias/nbias tiled loads: 8 coalesced dwordx4 (newest VMEM) ----
        f32x4 bt[4], nt_[4];
        #pragma unroll
        for (int t = 0; t < 4; t++) {
            bt[t]  = *reinterpret_cast<const f32x4*>(btb + c * 1024 + t * 256);
            nt_[t] = *reinterpret_cast<const f32x4*>(ntb + c * 1024 + t * 256);
        }
        // ---- counted drain: kill stage(c) [2 oldest], keep bias [8] ----
        __builtin_amdgcn_sched_barrier(0);
        asm volatile("s_waitcnt vmcnt(8)" ::: "memory");
        __builtin_amdgcn_s_barrier();
        __builtin_amdgcn_sched_barrier(0);
        // ---- issue stage(c+1) into the other buffer (safe: post-barrier) --
        if (c < 7) {
            char* dstb = (char*)kvlds[pb ^ 1] + wv * 1024;
            gl_lds16((const char*)kbase + (size_t)((c + 1) << 12) + ksrc0, dstb);
            gl_lds16((const char*)vbase + (size_t)((c + 1) << 7) + vsrc0, dstb + 4096);
        }
        // ---- QK^T from LDS K tile (swizzled read) ----
        const char* kl = (const char*)kvlds[pb];
        f32x4 sc[4];
        #pragma unroll
        for (int t = 0; t < 4; t++) {
            int kr = t * 16 + c15;
            bf16x8 kf = *reinterpret_cast<const bf16x8*>(kl + (kr << 6) + ((rgrp << 4) ^ ((kr & 3) << 4)));
            sc[t] = __builtin_amdgcn_mfma_f32_16x16x32_bf16(kf, aq, zML, 0, 0, 0);
        }
        // ---- softmax: e = exp2(fma(bb, L, sc)); pack P via cvt_pk ----
        f32x4 es[4];
        #pragma unroll
        for (int t = 0; t < 4; t++) {
            f32x4 bb = bt[t] + nt_[t];
            #pragma unroll
            for (int r = 0; r < 4; r++)
                es[t][r] = __builtin_amdgcn_exp2f(fmaf(bb[r], LOG2E, sc[t][r]));
            lsv += es[t];
        }
        unsigned int pw[8];
        #pragma unroll
        for (int t = 0; t < 4; t++) {
            asm("v_cvt_pk_bf16_f32 %0, %1, %2" : "=v"(pw[t * 2 + 0]) : "v"(es[t][0]), "v"(es[t][1]));
            asm("v_cvt_pk_bf16_f32 %0, %1, %2" : "=v"(pw[t * 2 + 1]) : "v"(es[t][2]), "v"(es[t][3]));
        }
        u32x4 a0 = {pw[0], pw[1], pw[2], pw[3]};
        u32x4 a1 = {pw[4], pw[5], pw[6], pw[7]};
        bf16x8 pa0 = __builtin_bit_cast(bf16x8, a0);
        bf16x8 pa1 = __builtin_bit_cast(bf16x8, a1);
        // ---- PV from LDS V tile (swizzled read), P in-register ----
        #pragma unroll
        for (int sub = 0; sub < 2; sub++) {
            bf16x8 ap = sub == 0 ? pa0 : pa1;
            #pragma unroll
            for (int nt = 0; nt < 2; nt++) {
                int vr = nt * 16 + c15;
                bf16x8 bv = *reinterpret_cast<const bf16x8*>(kl + 4096 + (vr << 7)
                                + (((sub << 6) | (rgrp << 4)) ^ ((vr & 7) << 4)));
                o[nt] = __builtin_amdgcn_mfma_f32_16x16x32_bf16(ap, bv, o[nt], 0, 0, 0);
            }
        }
    }

    float lsum = (lsv[0] + lsv[1]) + (lsv[2] + lsv[3]);
    lsum += __shfl_xor(lsum, 16, 64);
    lsum += __shfl_xor(lsum, 32, 64);
    float linv[4];
    #pragma unroll
    for (int r = 0; r < 4; r++)
        linv[r] = 1.f / __shfl(lsum, rgrp * 4 + r, 64);

    // epilogue: normalize, gate, store wa as bf16 [B,Q,H*HD]
    const bf16_t* gptr = gateb + (size_t)(b * Hn + h) * Qn * HDn;
    bf16_t* wptr = wab + (size_t)b * Qn * 256;
    const int qg = q0 + rgrp * 4;
    #pragma unroll
    for (int nt = 0; nt < 2; nt++) {
        int d = nt * 16 + c15;
        #pragma unroll
        for (int r = 0; r < 4; r++) {
            float g = (float)gptr[(qg + r) * HDn + d];
            wptr[(qg + r) * 256 + h * 32 + d] = tob(o[nt][r] * linv[r] * g);
        }
    }
}

// ---------------- output projection + bias ----------------
__global__ __launch_bounds__(256) void outproj_kernel(
    const bf16_t* __restrict__ wab, const bf16_t* __restrict__ wto,
    const float* __restrict__ outb, float* __restrict__ out)
{
    __shared__ bf16_t alds[64 * ALDS_STRIDE];
    const int m0 = blockIdx.x * 64;
    const int tid = threadIdx.x;
    const int lane = tid & 63;
    const int w = tid >> 6;
    const int ncb = w * 64;
    const int c15 = lane & 15;
    const int rgrp = lane >> 4;
    const int kof = rgrp * 8;

    #pragma unroll
    for (int i = 0; i < 8; i++) {
        int u = tid + i * 256;
        int row = u >> 5;
        int c16 = u & 31;
        bf16x8 a8 = *reinterpret_cast<const bf16x8*>(wab + (size_t)(m0 + row) * 256 + c16 * 8);
        *reinterpret_cast<bf16x8*>(&alds[row * ALDS_STRIDE + c16 * 8]) = a8;
    }
    __syncthreads();

    f32x4 acc[4][4] = {};
    #pragma unroll
    for (int kc = 0; kc < 8; kc++) {
        bf16x8 am[4], bn[4];
        #pragma unroll
        for (int i = 0; i < 4; i++)
            am[i] = *reinterpret_cast<const bf16x8*>(&alds[(i * 16 + c15) * ALDS_STRIDE + kc * 32 + kof]);
        #pragma unroll
        for (int j = 0; j < 4; j++)
            bn[j] = *reinterpret_cast<const bf16x8*>(wto + (ncb + j * 16 + c15) * 256 + kc * 32 + kof);
        #pragma unroll
        for (int i = 0; i < 4; i++)
            #pragma unroll
            for (int j = 0; j < 4; j++)
                acc[i][j] = __builtin_amdgcn_mfma_f32_16x16x32_bf16(am[i], bn[j], acc[i][j], 0, 0, 0);
    }

    #pragma unroll
    for (int j = 0; j < 4; j++) {
        int n = ncb + j * 16 + c15;
        float ob = outb[n];
        #pragma unroll
        for (int i = 0; i < 4; i++) {
            #pragma unroll
            for (int r = 0; r < 4; r++) {
                int m = m0 + i * 16 + rgrp * 4 + r;
                out[(size_t)m * 256 + n] = acc[i][j][r] + ob;
            }
        }
    }
}

extern "C" void kernel_launch(void* const* d_in, const int* in_sizes, int n_in,
                              void* d_out, int out_size, void* d_ws, size_t ws_size,
                              hipStream_t stream) {
    const float* q_data = (const float*)d_in[0];
    const float* m_data = (const float*)d_in[1];
    const float* bias = (const float*)d_in[2];
    const float* nbias = (const float*)d_in[3];
    const float* query_w = (const float*)d_in[4];
    const float* key_w = (const float*)d_in[5];
    const float* value_w = (const float*)d_in[6];
    const float* gating_w = (const float*)d_in[7];
    const float* gating_b = (const float*)d_in[8];
    const float* output_w = (const float*)d_in[9];
    const float* output_b = (const float*)d_in[10];
    float* out = (float*)d_out;

    char* ws = (char*)d_ws;
    const size_t WT = 256 * 256 * sizeof(bf16_t);
    const size_t PROJ = (size_t)Bb * Hn * Qn * HDn;      // bf16 elems
    bf16_t* wtq = (bf16_t*)(ws);
    bf16_t* wtk = (bf16_t*)(ws + WT);
    bf16_t* wtv = (bf16_t*)(ws + 2 * WT);
    bf16_t* wtg = (bf16_t*)(ws + 3 * WT);
    bf16_t* wto = (bf16_t*)(ws + 4 * WT);
    bf16_t* qb = (bf16_t*)(ws + 5 * WT);
    bf16_t* kb = qb + PROJ;
    bf16_t* vtb = kb + PROJ;
    bf16_t* gateb = vtb + PROJ;
    bf16_t* wab = gateb + PROJ;

    const size_t BASE = 5 * WT + 5 * PROJ * sizeof(bf16_t);
    const size_t BT_BYTES = (size_t)64 * 65536 * 16;     // 67.1 MB
    float* btile = (float*)(ws + BASE);
    float* ntile = (float*)(ws + BASE + BT_BYTES);

    prep_weights<<<1280, 256, 0, stream>>>(query_w, key_w, value_w, gating_w, output_w,
                                           wtq, wtk, wtv, wtg, wto);
    prep_bias<<<18432, 256, 0, stream>>>(bias, nbias, btile, ntile);
    proj_kernel<<<dim3(512, 2), 512, 0, stream>>>(q_data, m_data, wtq, wtk, wtv, wtg,
                                                  gating_b, qb, kb, vtb, gateb);
    attn_kernel<<<4096, 256, 0, stream>>>(qb, kb, vtb, gateb, btile, ntile, wab);
    outproj_kernel<<<512, 256, 0, stream>>>(wab, wto, output_b, out);
}

// Round 10
// 174.093 us; speedup vs baseline: 1.3226x; 1.0522x over previous
//
#include <hip/hip_runtime.h>
#include <math.h>

#define Bb 64
#define Qn 512
#define Kn 512
#define Cn 256
#define Hn 8
#define HDn 32
#define OUTn 256

typedef __bf16 bf16_t;
typedef __attribute__((ext_vector_type(4))) __bf16 bf16x4;
typedef __attribute__((ext_vector_type(8))) __bf16 bf16x8;
typedef __attribute__((ext_vector_type(4))) float f32x4;
typedef __attribute__((ext_vector_type(4))) unsigned int u32x4;

__device__ inline bf16_t tob(float f) {
    unsigned int u = __float_as_uint(f);
    u += 0x7fff + ((u >> 16) & 1);   // RNE
    unsigned short s = (unsigned short)(u >> 16);
    return __builtin_bit_cast(bf16_t, s);
}

// async global->LDS, 16B per lane; LDS dest = wave-uniform base + lane*16
__device__ inline void gl_lds16(const void* g, void* l) {
    __builtin_amdgcn_global_load_lds(
        (const __attribute__((address_space(1))) unsigned int*)g,
        (__attribute__((address_space(3))) unsigned int*)l, 16, 0, 0);
}

// ---------------- weight prep: cast to bf16, MFMA-fragment-tiled ----------
// R10: weights stored in the exact B-fragment order proj/outproj consume:
//   element (n, k) -> wt[ ((n>>4)*8 + (k>>5))*512 + lane*8 + (k&7) ],
//   lane = ((k>>3)&3)*16 + (n&15).
// A wave's bn[j] load becomes ONE contiguous 1KB read (was 16 scattered
// 64B segments at 25% utilization -- the R2-proven 1.5x pattern).
__global__ __launch_bounds__(256) void prep_weights(
    const float* __restrict__ qw, const float* __restrict__ kw,
    const float* __restrict__ vw, const float* __restrict__ gw,
    const float* __restrict__ ow,
    bf16_t* __restrict__ wtq, bf16_t* __restrict__ wtk,
    bf16_t* __restrict__ wtv, bf16_t* __restrict__ wtg,
    bf16_t* __restrict__ wto)
{
    int tid = blockIdx.x * 256 + threadIdx.x;   // 0 .. 5*65536-1
    int mat = tid >> 16;
    int rem = tid & 65535;
    int a = rem >> 8;    // source row (k dim)
    int n = rem & 255;   // source col (n dim)
    const float* src = mat == 0 ? qw : mat == 1 ? kw : mat == 2 ? vw : mat == 3 ? gw : ow;
    bf16_t* dst = mat == 0 ? wtq : mat == 1 ? wtk : mat == 2 ? wtv : mat == 3 ? wtg : wto;
    int nb = n >> 4, kb = a >> 5, rg = (a >> 3) & 3, e = a & 7, nl = n & 15;
    size_t idx = (((size_t)(nb * 8 + kb) * 64) + rg * 16 + nl) * 8 + e;
    dst[idx] = tob(src[a * 256 + n]);
}

// ---------------- bias tiling: rearrange to MFMA-fragment layout ----------
// btile[b][q16][c][t][lane][r] = bias[b][q16*16+(lane&15)][c*64+t*16+(lane>>4)*4+r]
// ntile[h][q16][c][t][lane][r] = nbias[h][same][same]
__global__ __launch_bounds__(256) void prep_bias(
    const float* __restrict__ bias, const float* __restrict__ nbias,
    float* __restrict__ btile, float* __restrict__ ntile)
{
    size_t vid = (size_t)blockIdx.x * 256 + threadIdx.x;   // one f32x4 each
    const size_t NB = (size_t)64 * 65536;                  // bias vec4 count
    int lane, t, c, q16;
    if (vid < NB) {
        lane = vid & 63; t = (vid >> 6) & 3; c = (vid >> 8) & 7; q16 = (vid >> 11) & 31;
        int b = vid >> 16;
        int row = q16 * 16 + (lane & 15);
        int col = c * 64 + t * 16 + (lane >> 4) * 4;
        f32x4 v = *reinterpret_cast<const f32x4*>(bias + ((size_t)b * Qn + row) * Kn + col);
        *reinterpret_cast<f32x4*>(btile + vid * 4) = v;
    } else {
        size_t nv = vid - NB;                              // 8*65536 vec4
        lane = nv & 63; t = (nv >> 6) & 3; c = (nv >> 8) & 7; q16 = (nv >> 11) & 31;
        int h = nv >> 16;
        int row = q16 * 16 + (lane & 15);
        int col = c * 64 + t * 16 + (lane >> 4) * 4;
        f32x4 v = *reinterpret_cast<const f32x4*>(nbias + ((size_t)h * Qn + row) * Kn + col);
        *reinterpret_cast<f32x4*>(ntile + nv * 4) = v;
    }
}

// ---------------- projections ----------------
// v is stored with a permuted k-axis so attention's PV step can consume P
// directly from the QK^T accumulator layout (no LDS transpose):
//   vbuf[d][kk] = V[pos][d],  kk = perm^-1(pos),
//   perm^-1 on low 5 bits: kk = p3<<4 | p2<<3 | p4<<2 | p1<<1 | p0.
// R9: epilogue restaged through LDS -> fully coalesced 16B stores.
// R10: B-fragments read from the tiled weight layout (1 contiguous 1KB
// line per wave-instr, addresses = base + imm offsets); A-staging uses
// v_cvt_pk_bf16_f32 + ds_write_b64 (4x fewer LDS writes, same RNE bits).
#define ALDS_STRIDE 264   // 256 + 8 pad
__global__ __launch_bounds__(512) void proj_kernel(
    const float* __restrict__ qdata, const float* __restrict__ mdata,
    const bf16_t* __restrict__ wtq, const bf16_t* __restrict__ wtk,
    const bf16_t* __restrict__ wtv, const bf16_t* __restrict__ wtg,
    const float* __restrict__ gating_b,
    bf16_t* __restrict__ qb, bf16_t* __restrict__ kb,
    bf16_t* __restrict__ vTb, bf16_t* __restrict__ gateb)
{
    __shared__ __align__(16) bf16_t smem[20480];   // A-tile (16896) / scratch (8x2560)
    bf16_t* alds = smem;
    const int side = blockIdx.y;          // 0: q_data, 1: m_data
    const int m0 = blockIdx.x * 64;
    const int tid = threadIdx.x;
    const int lane = tid & 63;
    const int w = tid >> 6;               // wave 0..7
    const int ch = w >> 2;                // 0: q|k, 1: gate|v
    const int ncb = (w & 3) * 64;
    const int c15 = lane & 15;
    const int rgrp = lane >> 4;
    const int kof = rgrp * 8;
    const float* X = side ? mdata : qdata;
    const bf16_t* Wt = side == 0 ? (ch == 0 ? wtq : wtg) : (ch == 0 ? wtk : wtv);
    const bool vout = (side == 1) && (ch == 1);

    #pragma unroll
    for (int i = 0; i < 8; i++) {
        int u = tid + i * 512;            // 4096 f32x4 units
        int row = u >> 6;
        int c4 = u & 63;
        f32x4 a4 = *reinterpret_cast<const f32x4*>(X + (size_t)(m0 + row) * 256 + c4 * 4);
        unsigned int p0, p1;
        asm("v_cvt_pk_bf16_f32 %0, %1, %2" : "=v"(p0) : "v"(a4[0]), "v"(a4[1]));
        asm("v_cvt_pk_bf16_f32 %0, %1, %2" : "=v"(p1) : "v"(a4[2]), "v"(a4[3]));
        unsigned long long pk = ((unsigned long long)p1 << 32) | p0;
        *reinterpret_cast<unsigned long long*>(&alds[row * ALDS_STRIDE + c4 * 4]) = pk;
    }
    __syncthreads();

    const bf16_t* wbase = Wt + (size_t)(ncb >> 4) * 8 * 512 + lane * 8;
    f32x4 acc[4][4] = {};
    #pragma unroll
    for (int kc = 0; kc < 8; kc++) {
        bf16x8 am[4], bn[4];
        #pragma unroll
        for (int i = 0; i < 4; i++)
            am[i] = *reinterpret_cast<const bf16x8*>(&alds[(i * 16 + c15) * ALDS_STRIDE + kc * 32 + kof]);
        #pragma unroll
        for (int j = 0; j < 4; j++)
            bn[j] = *reinterpret_cast<const bf16x8*>(wbase + ((size_t)j * 8 + kc) * 512);
        #pragma unroll
        for (int i = 0; i < 4; i++)
            #pragma unroll
            for (int j = 0; j < 4; j++) {
                if (vout)
                    acc[i][j] = __builtin_amdgcn_mfma_f32_16x16x32_bf16(bn[j], am[i], acc[i][j], 0, 0, 0);
                else
                    acc[i][j] = __builtin_amdgcn_mfma_f32_16x16x32_bf16(am[i], bn[j], acc[i][j], 0, 0, 0);
            }
    }

    __syncthreads();                      // all alds A-tile reads done; reuse as scratch
    bf16_t* scr = smem + w * 2560;        // per-wave slice, 16B-aligned

    // q is pre-scaled by log2(e)/sqrt(32): softmax computes exp2 directly.
    const float scale = 0.17677669529663687f * 1.4426950408889634f;
    const int hbase = ncb >> 5;
    const int posbase = m0 & 511;
    const int b = m0 >> 9;

    if (!vout) {
        bf16_t* dst = side == 0 ? (ch == 0 ? qb : gateb) : kb;
        #pragma unroll
        for (int P = 0; P < 2; P++) {
            // stage 2 i-slices (32 rows x 64 cols) -> scr[row][col], stride 72
            #pragma unroll
            for (int ii = 0; ii < 2; ii++) {
                int i = P * 2 + ii;
                #pragma unroll
                for (int j = 0; j < 4; j++) {
                    int n = ncb + j * 16 + c15;
                    #pragma unroll
                    for (int r = 0; r < 4; r++) {
                        float v = acc[i][j][r];
                        if (side == 0) {
                            if (ch == 0) v *= scale;
                            else v = 1.f / (1.f + __expf(-(v + gating_b[n])));
                        }
                        scr[(ii * 16 + rgrp * 4 + r) * 72 + j * 16 + c15] = tob(v);
                    }
                }
            }
            asm volatile("" ::: "memory");
            // coalesced write-out: 4 iters x 16B/lane, full 64B lines/instr
            #pragma unroll
            for (int v2 = 0; v2 < 4; v2++) {
                int row = v2 * 8 + (lane >> 3);
                int col = (lane & 7) * 8;
                bf16x8 val = *reinterpret_cast<const bf16x8*>(&scr[row * 72 + col]);
                int pos = posbase + P * 32 + row;
                int hh = hbase + (col >> 5);
                int d = col & 31;
                *reinterpret_cast<bf16x8*>(dst + (((size_t)(b * Hn + hh) * Qn + pos) << 5) + d) = val;
            }
            asm volatile("" ::: "memory");   // pass1 writes after pass0 reads
        }
    } else {
        // transposed acc: lanes index m-rows (key positions), regs index n=(h,d)
        // kk perm folded into the LDS WRITE column; readback is stride-1 in kk.
        #pragma unroll
        for (int P = 0; P < 2; P++) {
            #pragma unroll
            for (int ii = 0; ii < 2; ii++) {
                int i = P * 2 + ii;
                int kperm = (((c15 >> 3) & 1) << 4) | (((c15 >> 2) & 1) << 3) | (ii << 2)
                          | (((c15 >> 1) & 1) << 1) | (c15 & 1);
                #pragma unroll
                for (int j = 0; j < 4; j++)
                    #pragma unroll
                    for (int r = 0; r < 4; r++)
                        scr[(j * 16 + rgrp * 4 + r) * 40 + kperm] = tob(acc[i][j][r]);
            }
            asm volatile("" ::: "memory");
            #pragma unroll
            for (int u = 0; u < 4; u++) {
                int nloc = u * 16 + (lane >> 2);
                int koff = (lane & 3) * 8;
                bf16x8 val = *reinterpret_cast<const bf16x8*>(&scr[nloc * 40 + koff]);
                int hh = hbase + (nloc >> 5);
                int d = nloc & 31;
                *reinterpret_cast<bf16x8*>(vTb + ((size_t)(b * Hn + hh) * HDn + d) * Kn
                                           + posbase + P * 32 + koff) = val;
            }
            asm volatile("" ::: "memory");
        }
    }
}

// ---------------- fused attention, TILED-BIAS (R8, unchanged) -------------
// bias/nbias pre-tiled to fragment layout -> 8 coalesced dwordx4 per chunk
// straight to registers. LDS = 16KB kv dbuf only. Counted vmcnt(8): at the
// wait, outstanding = stage(c)[2 oldest] + bias(c)[8 newer].
__global__ __launch_bounds__(256) void attn_kernel(
    const bf16_t* __restrict__ qb, const bf16_t* __restrict__ kb,
    const bf16_t* __restrict__ vTb, const bf16_t* __restrict__ gateb,
    const float* __restrict__ btile, const float* __restrict__ ntile,
    bf16_t* __restrict__ wab)
{
    __shared__ __align__(16) char kvlds[2][8192];    // [buf][K 4KB | V 4KB]
    const int p = blockIdx.x;
    const int qt = p & 7;
    const int h = (p >> 3) & 7;
    const int b = p >> 6;
    const int lane = threadIdx.x & 63;
    const int wv = threadIdx.x >> 6;
    const int q0 = qt * 64 + wv * 16;
    const int q16 = qt * 4 + wv;
    const int c15 = lane & 15;
    const int rgrp = lane >> 4;
    const int kof = rgrp * 8;

    const bf16_t* qbase = qb + (size_t)(b * Hn + h) * Qn * HDn;
    const bf16_t* kbase = kb + (size_t)(b * Hn + h) * Kn * HDn;
    const bf16_t* vbase = vTb + (size_t)(b * Hn + h) * HDn * Kn;
    const float* btb = btile + (((size_t)b * 32 + q16) << 13) + lane * 4;   // 8192 f/q16
    const float* ntb = ntile + (((size_t)h * 32 + q16) << 13) + lane * 4;

    // staging lane geometry (constant per thread)
    const int krw = (wv << 4) + (lane >> 2);        // K row 0..63
    const int kcb = (lane & 3) << 4;                // K col byte
    const int vrw = (wv << 3) + (lane >> 3);        // V row 0..31
    const int vcb = (lane & 7) << 4;                // V col byte
    const size_t ksrc0 = ((size_t)krw << 6) + (size_t)(kcb ^ ((krw & 3) << 4));
    const size_t vsrc0 = ((size_t)vrw << 10) + (size_t)(vcb ^ ((vrw & 7) << 4));

    bf16x8 aq = *reinterpret_cast<const bf16x8*>(qbase + (q0 + c15) * HDn + kof);

    const float NML = -12.f * 1.4426950408889634f;   // -M*log2e, folded into QK^T C
    const float LOG2E = 1.4426950408889634f;
    const f32x4 zML = {NML, NML, NML, NML};
    f32x4 o[2] = {};
    f32x4 lsv = {0.f, 0.f, 0.f, 0.f};

    // ---- prologue: stage chunk 0 -> LDS buf 0 ----
    gl_lds16((const char*)kbase + ksrc0, (char*)kvlds[0] + wv * 1024);
    gl_lds16((const char*)vbase + vsrc0, (char*)kvlds[0] + 4096 + wv * 1024);

    #pragma unroll 1
    for (int c = 0; c < 8; c++) {         // 8 chunks of 64 k-cols
        const int pb = c & 1;
        // ---- bias/nbias tiled loads: 8 coalesced dwordx4 (newest VMEM) ----
        f32x4 bt[4], nt_[4];
        #pragma unroll
        for (int t = 0; t < 4; t++) {
            bt[t]  = *reinterpret_cast<const f32x4*>(btb + c * 1024 + t * 256);
            nt_[t] = *reinterpret_cast<const f32x4*>(ntb + c * 1024 + t * 256);
        }
        // ---- counted drain: kill stage(c) [2 oldest], keep bias [8] ----
        __builtin_amdgcn_sched_barrier(0);
        asm volatile("s_waitcnt vmcnt(8)" ::: "memory");
        __builtin_amdgcn_s_barrier();
        __builtin_amdgcn_sched_barrier(0);
        // ---- issue stage(c+1) into the other buffer (safe: post-barrier) --
        if (c < 7) {
            char* dstb = (char*)kvlds[pb ^ 1] + wv * 1024;
            gl_lds16((const char*)kbase + (size_t)((c + 1) << 12) + ksrc0, dstb);
            gl_lds16((const char*)vbase + (size_t)((c + 1) << 7) + vsrc0, dstb + 4096);
        }
        // ---- QK^T from LDS K tile (swizzled read) ----
        const char* kl = (const char*)kvlds[pb];
        f32x4 sc[4];
        #pragma unroll
        for (int t = 0; t < 4; t++) {
            int kr = t * 16 + c15;
            bf16x8 kf = *reinterpret_cast<const bf16x8*>(kl + (kr << 6) + ((rgrp << 4) ^ ((kr & 3) << 4)));
            sc[t] = __builtin_amdgcn_mfma_f32_16x16x32_bf16(kf, aq, zML, 0, 0, 0);
        }
        // ---- softmax: e = exp2(fma(bb, L, sc)); pack P via cvt_pk ----
        f32x4 es[4];
        #pragma unroll
        for (int t = 0; t < 4; t++) {
            f32x4 bb = bt[t] + nt_[t];
            #pragma unroll
            for (int r = 0; r < 4; r++)
                es[t][r] = __builtin_amdgcn_exp2f(fmaf(bb[r], LOG2E, sc[t][r]));
            lsv += es[t];
        }
        unsigned int pw[8];
        #pragma unroll
        for (int t = 0; t < 4; t++) {
            asm("v_cvt_pk_bf16_f32 %0, %1, %2" : "=v"(pw[t * 2 + 0]) : "v"(es[t][0]), "v"(es[t][1]));
            asm("v_cvt_pk_bf16_f32 %0, %1, %2" : "=v"(pw[t * 2 + 1]) : "v"(es[t][2]), "v"(es[t][3]));
        }
        u32x4 a0 = {pw[0], pw[1], pw[2], pw[3]};
        u32x4 a1 = {pw[4], pw[5], pw[6], pw[7]};
        bf16x8 pa0 = __builtin_bit_cast(bf16x8, a0);
        bf16x8 pa1 = __builtin_bit_cast(bf16x8, a1);
        // ---- PV from LDS V tile (swizzled read), P in-register ----
        #pragma unroll
        for (int sub = 0; sub < 2; sub++) {
            bf16x8 ap = sub == 0 ? pa0 : pa1;
            #pragma unroll
            for (int nt = 0; nt < 2; nt++) {
                int vr = nt * 16 + c15;
                bf16x8 bv = *reinterpret_cast<const bf16x8*>(kl + 4096 + (vr << 7)
                                + (((sub << 6) | (rgrp << 4)) ^ ((vr & 7) << 4)));
                o[nt] = __builtin_amdgcn_mfma_f32_16x16x32_bf16(ap, bv, o[nt], 0, 0, 0);
            }
        }
    }

    float lsum = (lsv[0] + lsv[1]) + (lsv[2] + lsv[3]);
    lsum += __shfl_xor(lsum, 16, 64);
    lsum += __shfl_xor(lsum, 32, 64);
    float linv[4];
    #pragma unroll
    for (int r = 0; r < 4; r++)
        linv[r] = 1.f / __shfl(lsum, rgrp * 4 + r, 64);

    // epilogue: normalize, gate, store wa as bf16 [B,Q,H*HD]
    const bf16_t* gptr = gateb + (size_t)(b * Hn + h) * Qn * HDn;
    bf16_t* wptr = wab + (size_t)b * Qn * 256;
    const int qg = q0 + rgrp * 4;
    #pragma unroll
    for (int nt = 0; nt < 2; nt++) {
        int d = nt * 16 + c15;
        #pragma unroll
        for (int r = 0; r < 4; r++) {
            float g = (float)gptr[(qg + r) * HDn + d];
            wptr[(qg + r) * 256 + h * 32 + d] = tob(o[nt][r] * linv[r] * g);
        }
    }
}

// ---------------- output projection + bias ----------------
__global__ __launch_bounds__(256) void outproj_kernel(
    const bf16_t* __restrict__ wab, const bf16_t* __restrict__ wto,
    const float* __restrict__ outb, float* __restrict__ out)
{
    __shared__ bf16_t alds[64 * ALDS_STRIDE];
    const int m0 = blockIdx.x * 64;
    const int tid = threadIdx.x;
    const int lane = tid & 63;
    const int w = tid >> 6;
    const int ncb = w * 64;
    const int c15 = lane & 15;
    const int rgrp = lane >> 4;
    const int kof = rgrp * 8;

    #pragma unroll
    for (int i = 0; i < 8; i++) {
        int u = tid + i * 256;
        int row = u >> 5;
        int c16 = u & 31;
        bf16x8 a8 = *reinterpret_cast<const bf16x8*>(wab + (size_t)(m0 + row) * 256 + c16 * 8);
        *reinterpret_cast<bf16x8*>(&alds[row * ALDS_STRIDE + c16 * 8]) = a8;
    }
    __syncthreads();

    const bf16_t* wbase = wto + (size_t)(ncb >> 4) * 8 * 512 + lane * 8;
    f32x4 acc[4][4] = {};
    #pragma unroll
    for (int kc = 0; kc < 8; kc++) {
        bf16x8 am[4], bn[4];
        #pragma unroll
        for (int i = 0; i < 4; i++)
            am[i] = *reinterpret_cast<const bf16x8*>(&alds[(i * 16 + c15) * ALDS_STRIDE + kc * 32 + kof]);
        #pragma unroll
        for (int j = 0; j < 4; j++)
            bn[j] = *reinterpret_cast<const bf16x8*>(wbase + ((size_t)j * 8 + kc) * 512);
        #pragma unroll
        for (int i = 0; i < 4; i++)
            #pragma unroll
            for (int j = 0; j < 4; j++)
                acc[i][j] = __builtin_amdgcn_mfma_f32_16x16x32_bf16(am[i], bn[j], acc[i][j], 0, 0, 0);
    }

    #pragma unroll
    for (int j = 0; j < 4; j++) {
        int n = ncb + j * 16 + c15;
        float ob = outb[n];
        #pragma unroll
        for (int i = 0; i < 4; i++) {
            #pragma unroll
            for (int r = 0; r < 4; r++) {
                int m = m0 + i * 16 + rgrp * 4 + r;
                out[(size_t)m * 256 + n] = acc[i][j][r] + ob;
            }
        }
    }
}

extern "C" void kernel_launch(void* const* d_in, const int* in_sizes, int n_in,
                              void* d_out, int out_size, void* d_ws, size_t ws_size,
                              hipStream_t stream) {
    const float* q_data = (const float*)d_in[0];
    const float* m_data = (const float*)d_in[1];
    const float* bias = (const float*)d_in[2];
    const float* nbias = (const float*)d_in[3];
    const float* query_w = (const float*)d_in[4];
    const float* key_w = (const float*)d_in[5];
    const float* value_w = (const float*)d_in[6];
    const float* gating_w = (const float*)d_in[7];
    const float* gating_b = (const float*)d_in[8];
    const float* output_w = (const float*)d_in[9];
    const float* output_b = (const float*)d_in[10];
    float* out = (float*)d_out;

    char* ws = (char*)d_ws;
    const size_t WT = 256 * 256 * sizeof(bf16_t);
    const size_t PROJ = (size_t)Bb * Hn * Qn * HDn;      // bf16 elems
    bf16_t* wtq = (bf16_t*)(ws);
    bf16_t* wtk = (bf16_t*)(ws + WT);
    bf16_t* wtv = (bf16_t*)(ws + 2 * WT);
    bf16_t* wtg = (bf16_t*)(ws + 3 * WT);
    bf16_t* wto = (bf16_t*)(ws + 4 * WT);
    bf16_t* qb = (bf16_t*)(ws + 5 * WT);
    bf16_t* kb = qb + PROJ;
    bf16_t* vtb = kb + PROJ;
    bf16_t* gateb = vtb + PROJ;
    bf16_t* wab = gateb + PROJ;

    const size_t BASE = 5 * WT + 5 * PROJ * sizeof(bf16_t);
    const size_t BT_BYTES = (size_t)64 * 65536 * 16;     // 67.1 MB
    float* btile = (float*)(ws + BASE);
    float* ntile = (float*)(ws + BASE + BT_BYTES);

    prep_weights<<<1280, 256, 0, stream>>>(query_w, key_w, value_w, gating_w, output_w,
                                           wtq, wtk, wtv, wtg, wto);
    prep_bias<<<18432, 256, 0, stream>>>(bias, nbias, btile, ntile);
    proj_kernel<<<dim3(512, 2), 512, 0, stream>>>(q_data, m_data, wtq, wtk, wtv, wtg,
                                                  gating_b, qb, kb, vtb, gateb);
    attn_kernel<<<4096, 256, 0, stream>>>(qb, kb, vtb, gateb, btile, ntile, wab);
    outproj_kernel<<<512, 256, 0, stream>>>(wab, wto, output_b, out);
}